// Round 8
// baseline (1013.169 us; speedup 1.0000x reference)
//
#include <hip/hip_runtime.h>
#include <math.h>

// B=2, S=2048, H=12, E(head width)=768=D, FF=3072
#define S_   2048
#define D_   768
#define HD_  9216
#define FF_  3072

typedef float  f32x4  __attribute__((ext_vector_type(4)));
typedef __bf16 bf16x8 __attribute__((ext_vector_type(8)));

__device__ __forceinline__ ushort f2bf(float v) {
    return __builtin_bit_cast(ushort, (__bf16)v);   // RNE fp32->bf16
}

// async global->LDS, 16B per lane; LDS dest = wave-uniform base + lane*16
__device__ __forceinline__ void load_lds16(const ushort* g, ushort* l) {
    __builtin_amdgcn_global_load_lds(
        (const __attribute__((address_space(1))) void*)g,
        (__attribute__((address_space(3))) void*)l, 16, 0, 0);
}

// ---------------------------------------------------------------------------
// 128x128 bf16 MFMA core. BK=32, LDS 32 KiB, depth-1 prefetch 2-phase
// (R4-proven schedule). Conflict-free XOR swizzle (R6-proven, BANK_CONFLICT=0):
// 16B chunk c of row r stored at LDS chunk c^((r>>1)&3) via source-permuted
// global address (LDS dest linear); same XOR on the ds_read side.
// acc += A[M,K]*Bt[N,K]^T, fp32 acc.
// ---------------------------------------------------------------------------
__device__ __forceinline__ void gemm128(
    const ushort* __restrict__ A, int lda,
    const ushort* __restrict__ Bt, int ldb,
    int m0, int n0, int kmax, f32x4 acc[4][4])
{
    __shared__ __align__(16) ushort As[2][128 * 32];
    __shared__ __align__(16) ushort Bs[2][128 * 32];
    const int tid  = threadIdx.x;
    const int lane = tid & 63, wave = tid >> 6;
    const int l16  = lane & 15, quad = lane >> 4;
    const int wr = wave >> 1, wc = wave & 1;
    const int srow = lane >> 2;                                  // 0..15
    const int scol = ((lane & 3) ^ ((srow >> 1) & 3)) << 3;      // swizzled src

    const ushort* Ab = A + (size_t)m0 * lda;
    const ushort* Bb = Bt + (size_t)n0 * ldb;

    auto stage = [&](int k0, int buf) {
#pragma unroll
        for (int c = 0; c < 2; ++c) {
            const int rb = c * 64 + wave * 16;                   // uniform base
            load_lds16(Ab + (size_t)(rb + srow) * lda + k0 + scol,
                       &As[buf][rb * 32]);
            load_lds16(Bb + (size_t)(rb + srow) * ldb + k0 + scol,
                       &Bs[buf][rb * 32]);
        }
    };

    stage(0, 0);
    __syncthreads();                       // buf0 ready
    const int csw = (quad ^ ((l16 >> 1) & 3)) << 3;
    int cur = 0;
    for (int k0 = 0; k0 < kmax; k0 += 32) {
        if (k0 + 32 < kmax) stage(k0 + 32, cur ^ 1);   // prefetch next tile
        bf16x8 a[4], b[4];
#pragma unroll
        for (int i = 0; i < 4; ++i)
            a[i] = *(const bf16x8*)&As[cur][(wr * 64 + i * 16 + l16) * 32 + csw];
#pragma unroll
        for (int j = 0; j < 4; ++j)
            b[j] = *(const bf16x8*)&Bs[cur][(wc * 64 + j * 16 + l16) * 32 + csw];
#pragma unroll
        for (int i = 0; i < 4; ++i)
#pragma unroll
            for (int j = 0; j < 4; ++j)
                acc[i][j] = __builtin_amdgcn_mfma_f32_16x16x32_bf16(
                    a[i], b[j], acc[i][j], 0, 0, 0);
        __syncthreads();                   // drains prefetch vmcnt; syncs reuse
        cur ^= 1;
    }
}

// ---------------------------------------------------------------------------
// 64x128 core (M=64), normal row-major A (pre-offset to its first row).
// 2x2 waves, each 32x64; acc[2][4]. LDS 24 KiB -> 6 blocks/CU ceiling.
// Same schedule + swizzle as gemm128.
// ---------------------------------------------------------------------------
__device__ __forceinline__ void gemm64(
    const ushort* __restrict__ A, int lda,
    const ushort* __restrict__ Bt, int ldb,
    int n0, int kmax, f32x4 acc[2][4])
{
    __shared__ __align__(16) ushort As[2][64 * 32];
    __shared__ __align__(16) ushort Bs[2][128 * 32];
    const int tid  = threadIdx.x;
    const int lane = tid & 63, wave = tid >> 6;
    const int l16  = lane & 15, quad = lane >> 4;
    const int wr = wave >> 1, wc = wave & 1;
    const int srow = lane >> 2;
    const int scol = ((lane & 3) ^ ((srow >> 1) & 3)) << 3;

    const ushort* Bb = Bt + (size_t)n0 * ldb;

    auto stage = [&](int k0, int buf) {
        {   // A: 64 rows, one load per wave
            const int rb = wave * 16;
            load_lds16(A + (size_t)(rb + srow) * lda + k0 + scol,
                       &As[buf][rb * 32]);
        }
#pragma unroll
        for (int c = 0; c < 2; ++c) {      // B: 128 rows
            const int rb = c * 64 + wave * 16;
            load_lds16(Bb + (size_t)(rb + srow) * ldb + k0 + scol,
                       &Bs[buf][rb * 32]);
        }
    };

    stage(0, 0);
    __syncthreads();
    const int csw = (quad ^ ((l16 >> 1) & 3)) << 3;
    int cur = 0;
    for (int k0 = 0; k0 < kmax; k0 += 32) {
        if (k0 + 32 < kmax) stage(k0 + 32, cur ^ 1);
        bf16x8 a[2], b[4];
#pragma unroll
        for (int i = 0; i < 2; ++i)
            a[i] = *(const bf16x8*)&As[cur][(wr * 32 + i * 16 + l16) * 32 + csw];
#pragma unroll
        for (int j = 0; j < 4; ++j)
            b[j] = *(const bf16x8*)&Bs[cur][(wc * 64 + j * 16 + l16) * 32 + csw];
#pragma unroll
        for (int i = 0; i < 2; ++i)
#pragma unroll
            for (int j = 0; j < 4; ++j)
                acc[i][j] = __builtin_amdgcn_mfma_f32_16x16x32_bf16(
                    a[i], b[j], acc[i][j], 0, 0, 0);
        __syncthreads();
        cur ^= 1;
    }
}

// ---------------------------------------------------------------------------
// 64x128 core, A in causally-compacted tile layout: element (r, k) lives at
// Ab[(k>>7)*16384 + r*128 + (k&127)], Ab points at the first row used.
// kmax multiple of 128.
// ---------------------------------------------------------------------------
__device__ __forceinline__ void gemm64_bA(
    const ushort* __restrict__ Ab,
    const ushort* __restrict__ Bt, int ldb,
    int n0, int kmax, f32x4 acc[2][4])
{
    __shared__ __align__(16) ushort As[2][64 * 32];
    __shared__ __align__(16) ushort Bs[2][128 * 32];
    const int tid  = threadIdx.x;
    const int lane = tid & 63, wave = tid >> 6;
    const int l16  = lane & 15, quad = lane >> 4;
    const int wr = wave >> 1, wc = wave & 1;
    const int srow = lane >> 2;
    const int scol = ((lane & 3) ^ ((srow >> 1) & 3)) << 3;

    const ushort* Bb = Bt + (size_t)n0 * ldb;

    auto stage = [&](int k0, int buf) {
        const ushort* At = Ab + (size_t)(k0 >> 7) * 16384 + (k0 & 127);
        {
            const int rb = wave * 16;
            load_lds16(At + (size_t)(rb + srow) * 128 + scol, &As[buf][rb * 32]);
        }
#pragma unroll
        for (int c = 0; c < 2; ++c) {
            const int rb = c * 64 + wave * 16;
            load_lds16(Bb + (size_t)(rb + srow) * ldb + k0 + scol,
                       &Bs[buf][rb * 32]);
        }
    };

    stage(0, 0);
    __syncthreads();
    const int csw = (quad ^ ((l16 >> 1) & 3)) << 3;
    int cur = 0;
    for (int k0 = 0; k0 < kmax; k0 += 32) {
        if (k0 + 32 < kmax) stage(k0 + 32, cur ^ 1);
        bf16x8 a[2], b[4];
#pragma unroll
        for (int i = 0; i < 2; ++i)
            a[i] = *(const bf16x8*)&As[cur][(wr * 32 + i * 16 + l16) * 32 + csw];
#pragma unroll
        for (int j = 0; j < 4; ++j)
            b[j] = *(const bf16x8*)&Bs[cur][(wc * 64 + j * 16 + l16) * 32 + csw];
#pragma unroll
        for (int i = 0; i < 2; ++i)
#pragma unroll
            for (int j = 0; j < 4; ++j)
                acc[i][j] = __builtin_amdgcn_mfma_f32_16x16x32_bf16(
                    a[i], b[j], acc[i][j], 0, 0, 0);
        __syncthreads();
        cur ^= 1;
    }
}

// epilogue index helpers (verified C/D layout: col=lane&15, row=quad*4+reg)
#define EPI_DECL \
    const int lane_ = threadIdx.x & 63, wave_ = threadIdx.x >> 6;   \
    const int l16_ = lane_ & 15, quad_ = lane_ >> 4;                \
    const int wr_ = wave_ >> 1, wc_ = wave_ & 1;
#define RR_ (wr_ * 64 + i * 16 + quad_ * 4 + r)
#define NC_ (wc_ * 64 + j * 16 + l16_)
#define RR64_ (wr_ * 32 + i * 16 + quad_ * 4 + r)

// ---------------------------------------------------------------------------
// fp32 -> bf16 convert (n multiple of 1024).
// ---------------------------------------------------------------------------
__global__ __launch_bounds__(256) void convert_kernel(
    const float* __restrict__ in, ushort* __restrict__ out, long n)
{
    long i = ((long)blockIdx.x * 256 + threadIdx.x) * 4;
    const long stride = (long)gridDim.x * 1024;
    for (; i < n; i += stride) {
        float4 v = *(const float4*)&in[i];
        out[i + 0] = f2bf(v.x); out[i + 1] = f2bf(v.y);
        out[i + 2] = f2bf(v.z); out[i + 3] = f2bf(v.w);
    }
}

// ---------------------------------------------------------------------------
// Weight folds, both in ONE launch. z<12: Mt_h = Wkb_h . Wqb_h^T.
// z>=12: Ut_h = Wob[:, h*768:+768] . Wvb_h^T. grid (6, 6, 24) = 864 blocks.
// ---------------------------------------------------------------------------
__global__ __launch_bounds__(256, 2) void fold_kernel(
    const ushort* __restrict__ Wqb, const ushort* __restrict__ Wkb,
    const ushort* __restrict__ Wvb, const ushort* __restrict__ Wob,
    ushort* __restrict__ Mt, ushort* __restrict__ Ut)
{
    const int z = blockIdx.z;
    const int m0 = blockIdx.y * 128, n0 = blockIdx.x * 128;
    f32x4 acc[4][4];
#pragma unroll
    for (int i = 0; i < 4; ++i)
#pragma unroll
        for (int j = 0; j < 4; ++j) acc[i][j] = (f32x4){0.f, 0.f, 0.f, 0.f};
    ushort* out;
    if (z < 12) {
        gemm128(Wkb + (size_t)z * 589824, 768, Wqb + (size_t)z * 589824, 768,
                m0, n0, 768, acc);
        out = Mt + (size_t)z * 589824;
    } else {
        const int h = z - 12;
        gemm128(Wob + (size_t)h * 768, HD_, Wvb + (size_t)h * 589824, 768,
                m0, n0, 768, acc);
        out = Ut + (size_t)h * 589824;
    }
    EPI_DECL
#pragma unroll
    for (int i = 0; i < 4; ++i)
#pragma unroll
        for (int j = 0; j < 4; ++j)
#pragma unroll
            for (int r = 0; r < 4; ++r)
                out[(size_t)(m0 + RR_) * D_ + n0 + NC_] = f2bf(acc[i][j][r]);
}

// ---------------------------------------------------------------------------
// XM + Y for one head pair. z=0,1: XM_h = x.Mt_h^T (normal write).
// z=2,3: Y_h = x.Ut_h^T, written TRANSPOSED: Yt[h][slab][768][2048].
// grid (6, 32, 4) = 768 blocks.
// ---------------------------------------------------------------------------
__global__ __launch_bounds__(256, 2) void xmy_kernel(
    const ushort* __restrict__ Xb, const ushort* __restrict__ MtP,
    const ushort* __restrict__ UtP, ushort* __restrict__ XMp,
    ushort* __restrict__ Yt)
{
    const int z = blockIdx.z;
    const int h = z & 1;
    const bool ymode = z >= 2;
    const int m0 = blockIdx.y * 128, n0 = blockIdx.x * 128;
    const ushort* Bt = (ymode ? UtP : MtP) + (size_t)h * 589824;
    f32x4 acc[4][4];
#pragma unroll
    for (int i = 0; i < 4; ++i)
#pragma unroll
        for (int j = 0; j < 4; ++j) acc[i][j] = (f32x4){0.f, 0.f, 0.f, 0.f};
    gemm128(Xb, D_, Bt, D_, m0, n0, D_, acc);
    EPI_DECL
    if (!ymode) {
        ushort* out = XMp + (size_t)h * 3145728;
#pragma unroll
        for (int i = 0; i < 4; ++i)
#pragma unroll
            for (int j = 0; j < 4; ++j)
#pragma unroll
                for (int r = 0; r < 4; ++r)
                    out[(size_t)(m0 + RR_) * D_ + n0 + NC_] = f2bf(acc[i][j][r]);
    } else {
        const int b = m0 >> 11;
        ushort* out = Yt + (size_t)h * 3145728 + (size_t)b * 1572864;
#pragma unroll
        for (int i = 0; i < 4; ++i)
#pragma unroll
            for (int j = 0; j < 4; ++j) {
                ushort4 o4;
                o4.x = f2bf(acc[i][j][0]); o4.y = f2bf(acc[i][j][1]);
                o4.z = f2bf(acc[i][j][2]); o4.w = f2bf(acc[i][j][3]);
                const int nc = n0 + wc_ * 64 + j * 16 + l16_;
                const int s  = (m0 & 2047) + wr_ * 64 + i * 16 + quad_ * 4;
                *(ushort4*)&out[(size_t)nc * 2048 + s] = o4;
            }
    }
}

// ---------------------------------------------------------------------------
// scores (compact, 64-row sub-tiles): bx = t*2+half; tile t=(mi,ni), ni<=mi.
// Sc half-tile = XM[64 rows].x^T (unscaled). grid (272, 2, 2) = 1088 blocks.
// ---------------------------------------------------------------------------
__global__ __launch_bounds__(256, 2) void scores_c_kernel(
    const ushort* __restrict__ XM, const ushort* __restrict__ Xb,
    ushort* __restrict__ Sc)
{
    const int bx = blockIdx.x;
    const int t = bx >> 1, half = bx & 1;
    const int b = blockIdx.y, hp = blockIdx.z;
    int mi = (int)((sqrtf(8.f * t + 1.f) - 1.f) * 0.5f);
    while ((mi + 1) * (mi + 2) / 2 <= t) ++mi;
    while (mi * (mi + 1) / 2 > t) --mi;
    const int ni = t - mi * (mi + 1) / 2;
    f32x4 acc[2][4];
#pragma unroll
    for (int i = 0; i < 2; ++i)
#pragma unroll
        for (int j = 0; j < 4; ++j) acc[i][j] = (f32x4){0.f, 0.f, 0.f, 0.f};
    gemm64(XM + (size_t)hp * 3145728 + (size_t)b * 1572864
              + (size_t)(mi * 128 + half * 64) * D_, D_,
           Xb + (size_t)b * 1572864, D_, ni * 128, D_, acc);
    ushort* out = Sc + ((size_t)(hp * 2 + b) * 136 + t) * 16384
                + (size_t)half * 64 * 128;
    EPI_DECL
#pragma unroll
    for (int i = 0; i < 2; ++i)
#pragma unroll
        for (int j = 0; j < 4; ++j)
#pragma unroll
            for (int r = 0; r < 4; ++r)
                out[(size_t)RR64_ * 128 + NC_] = f2bf(acc[i][j][r]);
}

// ---------------------------------------------------------------------------
// Causal softmax in place on compact tiles (scale 1/sqrt(768)); zeros k>q.
// Writes the FULL (mi+1)*128-wide row (zeros beyond q) -- py relies on this.
// Vectorized ushort4 access. grid (2 hp * 2 slab * 2048 rows) = 8192.
// ---------------------------------------------------------------------------
__global__ __launch_bounds__(256) void softmax_c_kernel(ushort* __restrict__ Sc)
{
    const int bx = blockIdx.x;
    const int hp = bx >> 12, b = (bx >> 11) & 1, q = bx & 2047;
    ushort* base = Sc + (size_t)((hp * 2 + b) * 136) * 16384;
    const int mi = q >> 7, tri = mi * (mi + 1) / 2;
    const int L  = (mi + 1) << 7;                   // row length
    const int ro = (q & 127) << 7;
    const float scale = 0.03608439182435161f;       // 1/sqrt(768)
    const int tid = threadIdx.x;
    const int wave = tid >> 6, lane = tid & 63;

    // element k lives at base[(tri + (k>>7))*16384 + ro + (k&127)]
    float xv[8];
    float m = -1e30f;
#pragma unroll
    for (int i = 0; i < 2; ++i) {
        const int k = tid * 4 + i * 1024;
        ushort4 v = {0, 0, 0, 0};
        if (k <= q)
            v = *(const ushort4*)&base[(size_t)(tri + (k >> 7)) * 16384
                                       + ro + (k & 127)];
        xv[i * 4 + 0] = (k + 0 <= q) ? (float)*(__bf16*)&v.x * scale : -1e30f;
        xv[i * 4 + 1] = (k + 1 <= q) ? (float)*(__bf16*)&v.y * scale : -1e30f;
        xv[i * 4 + 2] = (k + 2 <= q) ? (float)*(__bf16*)&v.z * scale : -1e30f;
        xv[i * 4 + 3] = (k + 3 <= q) ? (float)*(__bf16*)&v.w * scale : -1e30f;
#pragma unroll
        for (int j = 0; j < 4; ++j) m = fmaxf(m, xv[i * 4 + j]);
    }
    for (int o = 32; o > 0; o >>= 1) m = fmaxf(m, __shfl_xor(m, o));
    __shared__ float redm[4];
    if (lane == 0) redm[wave] = m;
    __syncthreads();
    m = fmaxf(fmaxf(redm[0], redm[1]), fmaxf(redm[2], redm[3]));

    float e[8];
    float s = 0.f;
#pragma unroll
    for (int i = 0; i < 2; ++i) {
        const int k = tid * 4 + i * 1024;
#pragma unroll
        for (int j = 0; j < 4; ++j) {
            e[i * 4 + j] = (k + j <= q) ? __expf(xv[i * 4 + j] - m) : 0.f;
            s += e[i * 4 + j];
        }
    }
    for (int o = 32; o > 0; o >>= 1) s += __shfl_xor(s, o);
    __shared__ float reds[4];
    if (lane == 0) reds[wave] = s;
    __syncthreads();
    s = reds[0] + reds[1] + reds[2] + reds[3];
    const float inv = 1.f / s;
#pragma unroll
    for (int i = 0; i < 2; ++i) {
        const int k = tid * 4 + i * 1024;
        if (k < L) {
            ushort4 o4;
            o4.x = f2bf(e[i * 4 + 0] * inv);
            o4.y = f2bf(e[i * 4 + 1] * inv);
            o4.z = f2bf(e[i * 4 + 2] * inv);
            o4.w = f2bf(e[i * 4 + 3] * inv);
            *(ushort4*)&base[(size_t)(tri + (k >> 7)) * 16384
                             + ro + (k & 127)] = o4;
        }
    }
}

// ---------------------------------------------------------------------------
// AttnH[h] += P_h . Y_h  (compact A, 64-row q-sub-tiles for occupancy).
// grid (6, 32, 4) = 768 blocks (3/CU); z=(h,b); heavy q-tiles first
// (mi64 = 31-by). Diagonal tile's masked half is zero-filled by softmax.
// NON-atomic +=: heads write disjoint accumulators (AttnA ws, AttnB d_out).
// ---------------------------------------------------------------------------
__global__ __launch_bounds__(256, 2) void py_kernel(
    const ushort* __restrict__ Sc, const ushort* __restrict__ Yt,
    float* __restrict__ AttnA, float* __restrict__ AttnB)
{
    const int z = blockIdx.z;
    const int h = z >> 1, b = z & 1;
    const int mi64 = 31 - blockIdx.y;      // 64-row q-sub-tile, heavy first
    const int mi   = mi64 >> 1;            // 128-row tile index
    const int n0 = blockIdx.x * 128;
    const ushort* Ab =
        Sc + ((size_t)(h * 2 + b) * 136 + mi * (mi + 1) / 2) * 16384
           + (size_t)(mi64 & 1) * 8192;    // 64-row offset inside tile
    const ushort* Bt = Yt + (size_t)h * 3145728 + (size_t)b * 1572864;
    f32x4 acc[2][4];
#pragma unroll
    for (int i = 0; i < 2; ++i)
#pragma unroll
        for (int j = 0; j < 4; ++j) acc[i][j] = (f32x4){0.f, 0.f, 0.f, 0.f};
    gemm64_bA(Ab, Bt, S_, n0, (mi + 1) << 7, acc);
    float* out = (h ? AttnB : AttnA) + (size_t)b * 1572864
               + (size_t)mi64 * 64 * D_;
    EPI_DECL
#pragma unroll
    for (int i = 0; i < 2; ++i)
#pragma unroll
        for (int j = 0; j < 4; ++j)
#pragma unroll
            for (int r = 0; r < 4; ++r)
                out[(size_t)RR64_ * D_ + n0 + NC_] += acc[i][j][r];
}

// ---------------------------------------------------------------------------
// LayerNorm (no affine, eps=1e-5) of (AttnA+AttnB): fp32 in -> bf16 out.
// grid (4096).
// ---------------------------------------------------------------------------
__global__ __launch_bounds__(256) void ln_kernel(
    const float* __restrict__ AttnA, const float* __restrict__ AttnB,
    ushort* __restrict__ Ln)
{
    const int row = blockIdx.x;
    const float* a = AttnA + (size_t)row * D_;
    const float* b = AttnB + (size_t)row * D_;
    const int tid = threadIdx.x;
    const int wave = tid >> 6, lane = tid & 63;
    float v0 = a[tid]       + b[tid];
    float v1 = a[tid + 256] + b[tid + 256];
    float v2 = a[tid + 512] + b[tid + 512];
    float s  = v0 + v1 + v2;
    float sq = v0 * v0 + v1 * v1 + v2 * v2;
    for (int o = 32; o > 0; o >>= 1) { s += __shfl_xor(s, o); sq += __shfl_xor(sq, o); }
    __shared__ float rs[4], rq[4];
    if (lane == 0) { rs[wave] = s; rq[wave] = sq; }
    __syncthreads();
    s  = rs[0] + rs[1] + rs[2] + rs[3];
    sq = rq[0] + rq[1] + rq[2] + rq[3];
    const float mean = s * (1.f / 768.f);
    float var = sq * (1.f / 768.f) - mean * mean;
    var = fmaxf(var, 0.f);
    const float rstd = rsqrtf(var + 1e-5f);
    ushort* o = Ln + (size_t)row * D_;
    o[tid]       = f2bf((v0 - mean) * rstd);
    o[tid + 256] = f2bf((v1 - mean) * rstd);
    o[tid + 512] = f2bf((v2 - mean) * rstd);
}

// ---------------------------------------------------------------------------
// FFN1 + exact GELU: H1 = gelu(Ln . F1b^T), [4096,3072]. grid (24, 32).
// ---------------------------------------------------------------------------
__global__ __launch_bounds__(256, 2) void ffn1_kernel(
    const ushort* __restrict__ Ln, const ushort* __restrict__ F1b,
    ushort* __restrict__ H1)
{
    const int m0 = blockIdx.y * 128, n0 = blockIdx.x * 128;
    f32x4 acc[4][4];
#pragma unroll
    for (int i = 0; i < 4; ++i)
#pragma unroll
        for (int j = 0; j < 4; ++j) acc[i][j] = (f32x4){0.f, 0.f, 0.f, 0.f};
    gemm128(Ln, D_, F1b, D_, m0, n0, D_, acc);
    EPI_DECL
#pragma unroll
    for (int i = 0; i < 4; ++i)
#pragma unroll
        for (int j = 0; j < 4; ++j)
#pragma unroll
            for (int r = 0; r < 4; ++r) {
                float v = acc[i][j][r];
                float gl = 0.5f * v * (1.f + erff(v * 0.70710678118654752f));
                H1[(size_t)(m0 + RR_) * FF_ + n0 + NC_] = f2bf(gl);
            }
}

// ---------------------------------------------------------------------------
// FFN2 split-K=2, 64-row M-tiles: P2[z] = H1[:, z*1536:+1536] . F2b^T slice.
// grid (6, 64, 2) = 768 blocks (3/CU). No atomics.
// ---------------------------------------------------------------------------
__global__ __launch_bounds__(256, 2) void ffn2p_kernel(
    const ushort* __restrict__ H1, const ushort* __restrict__ F2b,
    float* __restrict__ P2)
{
    const int z = blockIdx.z;
    const int m0 = blockIdx.y * 64, n0 = blockIdx.x * 128;
    f32x4 acc[2][4];
#pragma unroll
    for (int i = 0; i < 2; ++i)
#pragma unroll
        for (int j = 0; j < 4; ++j) acc[i][j] = (f32x4){0.f, 0.f, 0.f, 0.f};
    gemm64(H1 + (size_t)m0 * FF_ + (size_t)z * 1536, FF_,
           F2b + (size_t)z * 1536, FF_, n0, 1536, acc);
    float* out = P2 + (size_t)z * 3145728 + (size_t)m0 * D_;
    EPI_DECL
#pragma unroll
    for (int i = 0; i < 2; ++i)
#pragma unroll
        for (int j = 0; j < 4; ++j)
#pragma unroll
            for (int r = 0; r < 4; ++r)
                out[(size_t)RR64_ * D_ + n0 + NC_] = acc[i][j][r];
}

// ---------------------------------------------------------------------------
// FFN2 reduce + residual: Out = P2[0] + P2[1] + AttnA + AttnB.
// Out aliases AttnB (d_out): elementwise read-then-write, safe. grid (3072).
// ---------------------------------------------------------------------------
__global__ __launch_bounds__(256) void ffn2r_kernel(
    const float* __restrict__ P2, const float* __restrict__ AttnA,
    float* __restrict__ Out)
{
    const long i = ((long)blockIdx.x * 256 + threadIdx.x) * 4;
    float4 a = *(const float4*)&P2[i];
    float4 b = *(const float4*)&P2[3145728 + i];
    float4 c = *(const float4*)&AttnA[i];
    float4 d = *(const float4*)&Out[i];
    float4 o;
    o.x = a.x + b.x + c.x + d.x; o.y = a.y + b.y + c.y + d.y;
    o.z = a.z + b.z + c.z + d.z; o.w = a.w + b.w + c.w + d.w;
    *(float4*)&Out[i] = o;
}

// ---------------------------------------------------------------------------
// kernel_launch — algebraically fused attention:
//   Mt_h = Wk_h.Wq_h^T, Ut_h = Wo_h.Wv_h^T  (one merged 864-block launch)
//   per pair: {XM_h = x.Mt^T, Yt_h = (x.Ut^T)^T} ; Sc = XM.x^T (compact,
//   64-row blocks) ; softmax ; AttnH[h] += P.Y (64-row blocks, non-atomic)
// Workspace max offset 91,226,112 B.
// ---------------------------------------------------------------------------
extern "C" void kernel_launch(void* const* d_in, const int* in_sizes, int n_in,
                              void* d_out, int out_size, void* d_ws, size_t ws_size,
                              hipStream_t stream)
{
    // identify inputs by element count (x=3145728, ff=2359296, weights rest)
    int ix = -1, iw[4], nw = 0, iff[2], nf = 0;
    for (int i = 0; i < 7; ++i) {
        long sz = in_sizes[i];
        if (sz == 3145728L) ix = i;
        else if (sz == 2359296L) { if (nf < 2) iff[nf++] = i; }
        else { if (nw < 4) iw[nw++] = i; }
    }
    if (ix < 0 || nw != 4 || nf != 2) {
        ix = 0; iw[0] = 1; iw[1] = 2; iw[2] = 3; iw[3] = 4; iff[0] = 5; iff[1] = 6;
    }
    const float* x; const float *Wq, *Wk, *Wv, *Wo, *F1, *F2;
    x  = (const float*)d_in[ix];
    F1 = (const float*)d_in[iff[0]];
    F2 = (const float*)d_in[iff[1]];
    if (ix == 0) {           // dict order
        Wq = (const float*)d_in[iw[0]]; Wk = (const float*)d_in[iw[1]];
        Wv = (const float*)d_in[iw[2]]; Wo = (const float*)d_in[iw[3]];
    } else {                 // alphabetical
        Wk = (const float*)d_in[iw[0]]; Wo = (const float*)d_in[iw[1]];
        Wq = (const float*)d_in[iw[2]]; Wv = (const float*)d_in[iw[3]];
    }

    char* p = (char*)d_ws;
    // --- loop-phase layout ---
    ushort* Xb    = (ushort*)(p + 0);           // [4096,768] bf16      6,291,456
    ushort* Mt    = (ushort*)(p + 6291456);     // [12][768,768] bf16  14,155,776
    ushort* Ut    = (ushort*)(p + 20447232);    // [12][768,768] bf16  14,155,776
    float*  AttnA = (float*) (p + 34603008);    // [2][2048,768] fp32  12,582,912
    ushort* XMp   = (ushort*)(p + 47185920);    // [2][4096,768] bf16  12,582,912
    ushort* Yt    = (ushort*)(p + 59768832);    // [2][2][768,2048]    12,582,912
    ushort* Scp   = (ushort*)(p + 72351744);    // [2][2][136] tiles   17,825,792
    float*  AttnB = (float*)d_out;              // h=1 accumulator (12,582,912)
    // --- weight-fold transients (before loop; overlap AttnA/XMp/Yt/Scp) ---
    ushort* Wqb   = (ushort*)(p + 34603008);    // 14,155,776
    ushort* Wkb   = (ushort*)(p + 48758784);    // 14,155,776
    ushort* Wvb   = (ushort*)(p + 62914560);    // 14,155,776
    ushort* Wob   = (ushort*)(p + 77070336);    // 14,155,776 (ends 91,226,112)
    // --- FFN-phase layout (loop transients dead; AttnA preserved) ---
    ushort* H1    = (ushort*)(p + 0);           // [4096,3072] bf16    25,165,824
    ushort* F1b   = (ushort*)(p + 47185920);    // [3072,768] bf16      4,718,592
    ushort* F2b   = (ushort*)(p + 51904512);    // [768,3072] bf16      4,718,592
    ushort* Ln    = (ushort*)(p + 56623104);    // [4096,768] bf16      6,291,456
    float*  P2    = (float*) (p + 62914560);    // [2][4096,768] fp32  25,165,824

    dim3 blk(256);

    convert_kernel<<<dim3(1024), blk, 0, stream>>>(x,  Xb,  3145728L);
    convert_kernel<<<dim3(1024), blk, 0, stream>>>(Wq, Wqb, 7077888L);
    convert_kernel<<<dim3(1024), blk, 0, stream>>>(Wk, Wkb, 7077888L);
    convert_kernel<<<dim3(1024), blk, 0, stream>>>(Wv, Wvb, 7077888L);
    convert_kernel<<<dim3(1024), blk, 0, stream>>>(Wo, Wob, 7077888L);

    fold_kernel<<<dim3(6, 6, 24), blk, 0, stream>>>(Wqb, Wkb, Wvb, Wob, Mt, Ut);

    // weight buffers dead from here; AttnA region reusable
    hipMemsetAsync(AttnA, 0, 12582912, stream);
    hipMemsetAsync(AttnB, 0, 12582912, stream);

    for (int pr = 0; pr < 6; ++pr) {
        xmy_kernel<<<dim3(6, 32, 4), blk, 0, stream>>>(
            Xb, Mt + (size_t)pr * 1179648, Ut + (size_t)pr * 1179648,
            XMp, Yt);
        scores_c_kernel<<<dim3(272, 2, 2), blk, 0, stream>>>(XMp, Xb, Scp);
        softmax_c_kernel<<<dim3(8192), blk, 0, stream>>>(Scp);
        py_kernel<<<dim3(6, 32, 4), blk, 0, stream>>>(Scp, Yt, AttnA, AttnB);
    }

    convert_kernel<<<dim3(1024), blk, 0, stream>>>(F1, F1b, 2359296L);
    convert_kernel<<<dim3(1024), blk, 0, stream>>>(F2, F2b, 2359296L);
    ln_kernel<<<dim3(4096), blk, 0, stream>>>(AttnA, AttnB, Ln);
    ffn1_kernel<<<dim3(24, 32), blk, 0, stream>>>(Ln, F1b, H1);
    ffn2p_kernel<<<dim3(6, 64, 2), blk, 0, stream>>>(H1, F2b, P2);
    ffn2r_kernel<<<dim3(3072), blk, 0, stream>>>(P2, AttnA, (float*)d_out);
}

// Round 9
// 945.706 us; speedup vs baseline: 1.0713x; 1.0713x over previous
//
#include <hip/hip_runtime.h>
#include <math.h>

// B=2, S=2048, H=12, E(head width)=768=D, FF=3072
#define S_   2048
#define D_   768
#define HD_  9216
#define FF_  3072

typedef float  f32x4  __attribute__((ext_vector_type(4)));
typedef __bf16 bf16x8 __attribute__((ext_vector_type(8)));

__device__ __forceinline__ ushort f2bf(float v) {
    return __builtin_bit_cast(ushort, (__bf16)v);   // RNE fp32->bf16
}

// async global->LDS, 16B per lane; LDS dest = wave-uniform base + lane*16
__device__ __forceinline__ void load_lds16(const ushort* g, ushort* l) {
    __builtin_amdgcn_global_load_lds(
        (const __attribute__((address_space(1))) void*)g,
        (__attribute__((address_space(3))) void*)l, 16, 0, 0);
}

// ---------------------------------------------------------------------------
// Bijective XCD swizzle (T1): requires total grid % 8 == 0. Blocks with
// linear%8==c (which HW round-robins onto XCD c) get a CONTIGUOUS virtual
// range -> panel reuse becomes XCD-L2-local. Pure relabeling (bitwise-same).
// ---------------------------------------------------------------------------
__device__ __forceinline__ void xcd_swz(int& bx, int& by, int& bz) {
    const int gx = gridDim.x, gy = gridDim.y;
    const int nwg = gx * gy * (int)gridDim.z;
    int lin = bx + gx * (by + gy * bz);
    lin = (lin & 7) * (nwg >> 3) + (lin >> 3);
    bx = lin % gx;
    by = (lin / gx) % gy;
    bz = lin / (gx * gy);
}

// ---------------------------------------------------------------------------
// 128x128 bf16 MFMA core. BK=32, LDS 32 KiB, depth-1 prefetch 2-phase
// (R4-proven schedule). Conflict-free XOR swizzle (R6-proven, BANK_CONFLICT=0):
// 16B chunk c of row r stored at LDS chunk c^((r>>1)&3) via source-permuted
// global address (LDS dest linear); same XOR on the ds_read side.
// acc += A[M,K]*Bt[N,K]^T, fp32 acc.
// ---------------------------------------------------------------------------
__device__ __forceinline__ void gemm128(
    const ushort* __restrict__ A, int lda,
    const ushort* __restrict__ Bt, int ldb,
    int m0, int n0, int kmax, f32x4 acc[4][4])
{
    __shared__ __align__(16) ushort As[2][128 * 32];
    __shared__ __align__(16) ushort Bs[2][128 * 32];
    const int tid  = threadIdx.x;
    const int lane = tid & 63, wave = tid >> 6;
    const int l16  = lane & 15, quad = lane >> 4;
    const int wr = wave >> 1, wc = wave & 1;
    const int srow = lane >> 2;                                  // 0..15
    const int scol = ((lane & 3) ^ ((srow >> 1) & 3)) << 3;      // swizzled src

    const ushort* Ab = A + (size_t)m0 * lda;
    const ushort* Bb = Bt + (size_t)n0 * ldb;

    auto stage = [&](int k0, int buf) {
#pragma unroll
        for (int c = 0; c < 2; ++c) {
            const int rb = c * 64 + wave * 16;                   // uniform base
            load_lds16(Ab + (size_t)(rb + srow) * lda + k0 + scol,
                       &As[buf][rb * 32]);
            load_lds16(Bb + (size_t)(rb + srow) * ldb + k0 + scol,
                       &Bs[buf][rb * 32]);
        }
    };

    stage(0, 0);
    __syncthreads();                       // buf0 ready
    const int csw = (quad ^ ((l16 >> 1) & 3)) << 3;
    int cur = 0;
    for (int k0 = 0; k0 < kmax; k0 += 32) {
        if (k0 + 32 < kmax) stage(k0 + 32, cur ^ 1);   // prefetch next tile
        bf16x8 a[4], b[4];
#pragma unroll
        for (int i = 0; i < 4; ++i)
            a[i] = *(const bf16x8*)&As[cur][(wr * 64 + i * 16 + l16) * 32 + csw];
#pragma unroll
        for (int j = 0; j < 4; ++j)
            b[j] = *(const bf16x8*)&Bs[cur][(wc * 64 + j * 16 + l16) * 32 + csw];
#pragma unroll
        for (int i = 0; i < 4; ++i)
#pragma unroll
            for (int j = 0; j < 4; ++j)
                acc[i][j] = __builtin_amdgcn_mfma_f32_16x16x32_bf16(
                    a[i], b[j], acc[i][j], 0, 0, 0);
        __syncthreads();                   // drains prefetch vmcnt; syncs reuse
        cur ^= 1;
    }
}

// ---------------------------------------------------------------------------
// 64x128 core, A in causally-compacted tile layout: element (r, k) lives at
// Ab[(k>>7)*16384 + r*128 + (k&127)], Ab points at the first row used.
// kmax multiple of 128. 2x2 waves, each 32x64; acc[2][4]. LDS 24 KiB.
// ---------------------------------------------------------------------------
__device__ __forceinline__ void gemm64_bA(
    const ushort* __restrict__ Ab,
    const ushort* __restrict__ Bt, int ldb,
    int n0, int kmax, f32x4 acc[2][4])
{
    __shared__ __align__(16) ushort As[2][64 * 32];
    __shared__ __align__(16) ushort Bs[2][128 * 32];
    const int tid  = threadIdx.x;
    const int lane = tid & 63, wave = tid >> 6;
    const int l16  = lane & 15, quad = lane >> 4;
    const int wr = wave >> 1, wc = wave & 1;
    const int srow = lane >> 2;
    const int scol = ((lane & 3) ^ ((srow >> 1) & 3)) << 3;

    const ushort* Bb = Bt + (size_t)n0 * ldb;

    auto stage = [&](int k0, int buf) {
        const ushort* At = Ab + (size_t)(k0 >> 7) * 16384 + (k0 & 127);
        {
            const int rb = wave * 16;
            load_lds16(At + (size_t)(rb + srow) * 128 + scol, &As[buf][rb * 32]);
        }
#pragma unroll
        for (int c = 0; c < 2; ++c) {
            const int rb = c * 64 + wave * 16;
            load_lds16(Bb + (size_t)(rb + srow) * ldb + k0 + scol,
                       &Bs[buf][rb * 32]);
        }
    };

    stage(0, 0);
    __syncthreads();
    const int csw = (quad ^ ((l16 >> 1) & 3)) << 3;
    int cur = 0;
    for (int k0 = 0; k0 < kmax; k0 += 32) {
        if (k0 + 32 < kmax) stage(k0 + 32, cur ^ 1);
        bf16x8 a[2], b[4];
#pragma unroll
        for (int i = 0; i < 2; ++i)
            a[i] = *(const bf16x8*)&As[cur][(wr * 32 + i * 16 + l16) * 32 + csw];
#pragma unroll
        for (int j = 0; j < 4; ++j)
            b[j] = *(const bf16x8*)&Bs[cur][(wc * 64 + j * 16 + l16) * 32 + csw];
#pragma unroll
        for (int i = 0; i < 2; ++i)
#pragma unroll
            for (int j = 0; j < 4; ++j)
                acc[i][j] = __builtin_amdgcn_mfma_f32_16x16x32_bf16(
                    a[i], b[j], acc[i][j], 0, 0, 0);
        __syncthreads();
        cur ^= 1;
    }
}

// epilogue index helpers (verified C/D layout: col=lane&15, row=quad*4+reg)
#define EPI_DECL \
    const int lane_ = threadIdx.x & 63, wave_ = threadIdx.x >> 6;   \
    const int l16_ = lane_ & 15, quad_ = lane_ >> 4;                \
    const int wr_ = wave_ >> 1, wc_ = wave_ & 1;
#define RR_ (wr_ * 64 + i * 16 + quad_ * 4 + r)
#define NC_ (wc_ * 64 + j * 16 + l16_)
#define RR64_ (wr_ * 32 + i * 16 + quad_ * 4 + r)

// ---------------------------------------------------------------------------
// fp32 -> bf16 convert (n multiple of 1024).
// ---------------------------------------------------------------------------
__global__ __launch_bounds__(256) void convert_kernel(
    const float* __restrict__ in, ushort* __restrict__ out, long n)
{
    long i = ((long)blockIdx.x * 256 + threadIdx.x) * 4;
    const long stride = (long)gridDim.x * 1024;
    for (; i < n; i += stride) {
        float4 v = *(const float4*)&in[i];
        out[i + 0] = f2bf(v.x); out[i + 1] = f2bf(v.y);
        out[i + 2] = f2bf(v.z); out[i + 3] = f2bf(v.w);
    }
}

// ---------------------------------------------------------------------------
// Weight folds, both in ONE launch. z<12: Mt_h = Wkb_h . Wqb_h^T.
// z>=12: Ut_h = Wob[:, h*768:+768] . Wvb_h^T. grid (6, 6, 24) = 864 blocks.
// XCD-swizzled: each XCD works 3 contiguous z-slices (panels ~2.4MB -> L2).
// ---------------------------------------------------------------------------
__global__ __launch_bounds__(256, 2) void fold_kernel(
    const ushort* __restrict__ Wqb, const ushort* __restrict__ Wkb,
    const ushort* __restrict__ Wvb, const ushort* __restrict__ Wob,
    ushort* __restrict__ Mt, ushort* __restrict__ Ut)
{
    int bx = blockIdx.x, by = blockIdx.y, bz = blockIdx.z;
    xcd_swz(bx, by, bz);
    const int z = bz;
    const int m0 = by * 128, n0 = bx * 128;
    f32x4 acc[4][4];
#pragma unroll
    for (int i = 0; i < 4; ++i)
#pragma unroll
        for (int j = 0; j < 4; ++j) acc[i][j] = (f32x4){0.f, 0.f, 0.f, 0.f};
    ushort* out;
    if (z < 12) {
        gemm128(Wkb + (size_t)z * 589824, 768, Wqb + (size_t)z * 589824, 768,
                m0, n0, 768, acc);
        out = Mt + (size_t)z * 589824;
    } else {
        const int h = z - 12;
        gemm128(Wob + (size_t)h * 768, HD_, Wvb + (size_t)h * 589824, 768,
                m0, n0, 768, acc);
        out = Ut + (size_t)h * 589824;
    }
    EPI_DECL
#pragma unroll
    for (int i = 0; i < 4; ++i)
#pragma unroll
        for (int j = 0; j < 4; ++j)
#pragma unroll
            for (int r = 0; r < 4; ++r)
                out[(size_t)(m0 + RR_) * D_ + n0 + NC_] = f2bf(acc[i][j][r]);
}

// ---------------------------------------------------------------------------
// XM + Y for one head pair. z=0,1: XM_h = x.Mt_h^T (normal write).
// z=2,3: Y_h = x.Ut_h^T, written TRANSPOSED: Yt[h][slab][768][2048].
// grid (6, 32, 4) = 768 blocks, XCD-swizzled.
// ---------------------------------------------------------------------------
__global__ __launch_bounds__(256, 2) void xmy_kernel(
    const ushort* __restrict__ Xb, const ushort* __restrict__ MtP,
    const ushort* __restrict__ UtP, ushort* __restrict__ XMp,
    ushort* __restrict__ Yt)
{
    int bx = blockIdx.x, by = blockIdx.y, bz = blockIdx.z;
    xcd_swz(bx, by, bz);
    const int z = bz;
    const int h = z & 1;
    const bool ymode = z >= 2;
    const int m0 = by * 128, n0 = bx * 128;
    const ushort* Bt = (ymode ? UtP : MtP) + (size_t)h * 589824;
    f32x4 acc[4][4];
#pragma unroll
    for (int i = 0; i < 4; ++i)
#pragma unroll
        for (int j = 0; j < 4; ++j) acc[i][j] = (f32x4){0.f, 0.f, 0.f, 0.f};
    gemm128(Xb, D_, Bt, D_, m0, n0, D_, acc);
    EPI_DECL
    if (!ymode) {
        ushort* out = XMp + (size_t)h * 3145728;
#pragma unroll
        for (int i = 0; i < 4; ++i)
#pragma unroll
            for (int j = 0; j < 4; ++j)
#pragma unroll
                for (int r = 0; r < 4; ++r)
                    out[(size_t)(m0 + RR_) * D_ + n0 + NC_] = f2bf(acc[i][j][r]);
    } else {
        const int b = m0 >> 11;
        ushort* out = Yt + (size_t)h * 3145728 + (size_t)b * 1572864;
#pragma unroll
        for (int i = 0; i < 4; ++i)
#pragma unroll
            for (int j = 0; j < 4; ++j) {
                ushort4 o4;
                o4.x = f2bf(acc[i][j][0]); o4.y = f2bf(acc[i][j][1]);
                o4.z = f2bf(acc[i][j][2]); o4.w = f2bf(acc[i][j][3]);
                const int nc = n0 + wc_ * 64 + j * 16 + l16_;
                const int s  = (m0 & 2047) + wr_ * 64 + i * 16 + quad_ * 4;
                *(ushort4*)&out[(size_t)nc * 2048 + s] = o4;
            }
    }
}

// ---------------------------------------------------------------------------
// scores (compact, 128^2 tiles — R7-proven): tile t=(mi,ni), ni<=mi;
// Sc tile = XM.x^T (unscaled). grid (136, 2, 2) = 544 blocks, XCD-swizzled.
// ---------------------------------------------------------------------------
__global__ __launch_bounds__(256, 2) void scores_c_kernel(
    const ushort* __restrict__ XM, const ushort* __restrict__ Xb,
    ushort* __restrict__ Sc)
{
    int bx = blockIdx.x, by = blockIdx.y, bz = blockIdx.z;
    xcd_swz(bx, by, bz);
    const int t = bx, b = by, hp = bz;
    int mi = (int)((sqrtf(8.f * t + 1.f) - 1.f) * 0.5f);
    while ((mi + 1) * (mi + 2) / 2 <= t) ++mi;
    while (mi * (mi + 1) / 2 > t) --mi;
    const int ni = t - mi * (mi + 1) / 2;
    f32x4 acc[4][4];
#pragma unroll
    for (int i = 0; i < 4; ++i)
#pragma unroll
        for (int j = 0; j < 4; ++j) acc[i][j] = (f32x4){0.f, 0.f, 0.f, 0.f};
    gemm128(XM + (size_t)hp * 3145728 + (size_t)b * 1572864, D_,
            Xb + (size_t)b * 1572864, D_, mi * 128, ni * 128, D_, acc);
    ushort* out = Sc + ((size_t)(hp * 2 + b) * 136 + t) * 16384;
    EPI_DECL
#pragma unroll
    for (int i = 0; i < 4; ++i)
#pragma unroll
        for (int j = 0; j < 4; ++j)
#pragma unroll
            for (int r = 0; r < 4; ++r)
                out[(size_t)RR_ * 128 + NC_] = f2bf(acc[i][j][r]);
}

// ---------------------------------------------------------------------------
// Causal softmax in place on compact tiles (scale 1/sqrt(768)); zeros k>q.
// Writes the FULL (mi+1)*128-wide row (zeros beyond q) -- py relies on this.
// Vectorized ushort4 access. grid (2 hp * 2 slab * 2048 rows) = 8192.
// ---------------------------------------------------------------------------
__global__ __launch_bounds__(256) void softmax_c_kernel(ushort* __restrict__ Sc)
{
    const int bx = blockIdx.x;
    const int hp = bx >> 12, b = (bx >> 11) & 1, q = bx & 2047;
    ushort* base = Sc + (size_t)((hp * 2 + b) * 136) * 16384;
    const int mi = q >> 7, tri = mi * (mi + 1) / 2;
    const int L  = (mi + 1) << 7;                   // row length
    const int ro = (q & 127) << 7;
    const float scale = 0.03608439182435161f;       // 1/sqrt(768)
    const int tid = threadIdx.x;
    const int wave = tid >> 6, lane = tid & 63;

    // element k lives at base[(tri + (k>>7))*16384 + ro + (k&127)]
    float xv[8];
    float m = -1e30f;
#pragma unroll
    for (int i = 0; i < 2; ++i) {
        const int k = tid * 4 + i * 1024;
        ushort4 v = {0, 0, 0, 0};
        if (k <= q)
            v = *(const ushort4*)&base[(size_t)(tri + (k >> 7)) * 16384
                                       + ro + (k & 127)];
        xv[i * 4 + 0] = (k + 0 <= q) ? (float)*(__bf16*)&v.x * scale : -1e30f;
        xv[i * 4 + 1] = (k + 1 <= q) ? (float)*(__bf16*)&v.y * scale : -1e30f;
        xv[i * 4 + 2] = (k + 2 <= q) ? (float)*(__bf16*)&v.z * scale : -1e30f;
        xv[i * 4 + 3] = (k + 3 <= q) ? (float)*(__bf16*)&v.w * scale : -1e30f;
#pragma unroll
        for (int j = 0; j < 4; ++j) m = fmaxf(m, xv[i * 4 + j]);
    }
    for (int o = 32; o > 0; o >>= 1) m = fmaxf(m, __shfl_xor(m, o));
    __shared__ float redm[4];
    if (lane == 0) redm[wave] = m;
    __syncthreads();
    m = fmaxf(fmaxf(redm[0], redm[1]), fmaxf(redm[2], redm[3]));

    float e[8];
    float s = 0.f;
#pragma unroll
    for (int i = 0; i < 2; ++i) {
        const int k = tid * 4 + i * 1024;
#pragma unroll
        for (int j = 0; j < 4; ++j) {
            e[i * 4 + j] = (k + j <= q) ? __expf(xv[i * 4 + j] - m) : 0.f;
            s += e[i * 4 + j];
        }
    }
    for (int o = 32; o > 0; o >>= 1) s += __shfl_xor(s, o);
    __shared__ float reds[4];
    if (lane == 0) reds[wave] = s;
    __syncthreads();
    s = reds[0] + reds[1] + reds[2] + reds[3];
    const float inv = 1.f / s;
#pragma unroll
    for (int i = 0; i < 2; ++i) {
        const int k = tid * 4 + i * 1024;
        if (k < L) {
            ushort4 o4;
            o4.x = f2bf(e[i * 4 + 0] * inv);
            o4.y = f2bf(e[i * 4 + 1] * inv);
            o4.z = f2bf(e[i * 4 + 2] * inv);
            o4.w = f2bf(e[i * 4 + 3] * inv);
            *(ushort4*)&base[(size_t)(tri + (k >> 7)) * 16384
                             + ro + (k & 127)] = o4;
        }
    }
}

// ---------------------------------------------------------------------------
// AttnH[h] += P_h . Y_h  (compact A, 64-row q-sub-tiles for occupancy).
// grid (6, 32, 4) = 768 blocks (3/CU); z=(h,b); heavy q-tiles first
// (mi64 = 31-by, NOT swizzled: keeps heavy-first global order).
// Diagonal tile's masked half is zero-filled by softmax. NON-atomic +=:
// heads write disjoint accumulators (AttnA ws, AttnB d_out).
// ---------------------------------------------------------------------------
__global__ __launch_bounds__(256, 2) void py_kernel(
    const ushort* __restrict__ Sc, const ushort* __restrict__ Yt,
    float* __restrict__ AttnA, float* __restrict__ AttnB)
{
    const int z = blockIdx.z;
    const int h = z >> 1, b = z & 1;
    const int mi64 = 31 - blockIdx.y;      // 64-row q-sub-tile, heavy first
    const int mi   = mi64 >> 1;            // 128-row tile index
    const int n0 = blockIdx.x * 128;
    const ushort* Ab =
        Sc + ((size_t)(h * 2 + b) * 136 + mi * (mi + 1) / 2) * 16384
           + (size_t)(mi64 & 1) * 8192;    // 64-row offset inside tile
    const ushort* Bt = Yt + (size_t)h * 3145728 + (size_t)b * 1572864;
    f32x4 acc[2][4];
#pragma unroll
    for (int i = 0; i < 2; ++i)
#pragma unroll
        for (int j = 0; j < 4; ++j) acc[i][j] = (f32x4){0.f, 0.f, 0.f, 0.f};
    gemm64_bA(Ab, Bt, S_, n0, (mi + 1) << 7, acc);
    float* out = (h ? AttnB : AttnA) + (size_t)b * 1572864
               + (size_t)mi64 * 64 * D_;
    EPI_DECL
#pragma unroll
    for (int i = 0; i < 2; ++i)
#pragma unroll
        for (int j = 0; j < 4; ++j)
#pragma unroll
            for (int r = 0; r < 4; ++r)
                out[(size_t)RR64_ * D_ + n0 + NC_] += acc[i][j][r];
}

// ---------------------------------------------------------------------------
// LayerNorm (no affine, eps=1e-5) of (AttnA+AttnB): fp32 in -> bf16 out.
// grid (4096).
// ---------------------------------------------------------------------------
__global__ __launch_bounds__(256) void ln_kernel(
    const float* __restrict__ AttnA, const float* __restrict__ AttnB,
    ushort* __restrict__ Ln)
{
    const int row = blockIdx.x;
    const float* a = AttnA + (size_t)row * D_;
    const float* b = AttnB + (size_t)row * D_;
    const int tid = threadIdx.x;
    const int wave = tid >> 6, lane = tid & 63;
    float v0 = a[tid]       + b[tid];
    float v1 = a[tid + 256] + b[tid + 256];
    float v2 = a[tid + 512] + b[tid + 512];
    float s  = v0 + v1 + v2;
    float sq = v0 * v0 + v1 * v1 + v2 * v2;
    for (int o = 32; o > 0; o >>= 1) { s += __shfl_xor(s, o); sq += __shfl_xor(sq, o); }
    __shared__ float rs[4], rq[4];
    if (lane == 0) { rs[wave] = s; rq[wave] = sq; }
    __syncthreads();
    s  = rs[0] + rs[1] + rs[2] + rs[3];
    sq = rq[0] + rq[1] + rq[2] + rq[3];
    const float mean = s * (1.f / 768.f);
    float var = sq * (1.f / 768.f) - mean * mean;
    var = fmaxf(var, 0.f);
    const float rstd = rsqrtf(var + 1e-5f);
    ushort* o = Ln + (size_t)row * D_;
    o[tid]       = f2bf((v0 - mean) * rstd);
    o[tid + 256] = f2bf((v1 - mean) * rstd);
    o[tid + 512] = f2bf((v2 - mean) * rstd);
}

// ---------------------------------------------------------------------------
// FFN1 + exact GELU: H1 = gelu(Ln . F1b^T), [4096,3072]. grid (24, 32),
// XCD-swizzled.
// ---------------------------------------------------------------------------
__global__ __launch_bounds__(256, 2) void ffn1_kernel(
    const ushort* __restrict__ Ln, const ushort* __restrict__ F1b,
    ushort* __restrict__ H1)
{
    int bx = blockIdx.x, by = blockIdx.y, bz = blockIdx.z;
    xcd_swz(bx, by, bz);
    const int m0 = by * 128, n0 = bx * 128;
    f32x4 acc[4][4];
#pragma unroll
    for (int i = 0; i < 4; ++i)
#pragma unroll
        for (int j = 0; j < 4; ++j) acc[i][j] = (f32x4){0.f, 0.f, 0.f, 0.f};
    gemm128(Ln, D_, F1b, D_, m0, n0, D_, acc);
    EPI_DECL
#pragma unroll
    for (int i = 0; i < 4; ++i)
#pragma unroll
        for (int j = 0; j < 4; ++j)
#pragma unroll
            for (int r = 0; r < 4; ++r) {
                float v = acc[i][j][r];
                float gl = 0.5f * v * (1.f + erff(v * 0.70710678118654752f));
                H1[(size_t)(m0 + RR_) * FF_ + n0 + NC_] = f2bf(gl);
            }
}

// ---------------------------------------------------------------------------
// FFN2 split-K=2 (128-row, R7-proven): P2[z] = H1[:,z*1536:+1536].F2b^T slice.
// grid (6, 32, 2) = 384 blocks, XCD-swizzled. No atomics.
// ---------------------------------------------------------------------------
__global__ __launch_bounds__(256, 2) void ffn2p_kernel(
    const ushort* __restrict__ H1, const ushort* __restrict__ F2b,
    float* __restrict__ P2)
{
    int bx = blockIdx.x, by = blockIdx.y, bz = blockIdx.z;
    xcd_swz(bx, by, bz);
    const int z = bz;
    const int m0 = by * 128, n0 = bx * 128;
    f32x4 acc[4][4];
#pragma unroll
    for (int i = 0; i < 4; ++i)
#pragma unroll
        for (int j = 0; j < 4; ++j) acc[i][j] = (f32x4){0.f, 0.f, 0.f, 0.f};
    gemm128(H1 + (size_t)z * 1536, FF_, F2b + (size_t)z * 1536, FF_,
            m0, n0, 1536, acc);
    float* out = P2 + (size_t)z * 3145728;
    EPI_DECL
#pragma unroll
    for (int i = 0; i < 4; ++i)
#pragma unroll
        for (int j = 0; j < 4; ++j)
#pragma unroll
            for (int r = 0; r < 4; ++r)
                out[(size_t)(m0 + RR_) * D_ + n0 + NC_] = acc[i][j][r];
}

// ---------------------------------------------------------------------------
// FFN2 reduce + residual: Out = P2[0] + P2[1] + AttnA + AttnB.
// Out aliases AttnB (d_out): elementwise read-then-write, safe. grid (3072).
// ---------------------------------------------------------------------------
__global__ __launch_bounds__(256) void ffn2r_kernel(
    const float* __restrict__ P2, const float* __restrict__ AttnA,
    float* __restrict__ Out)
{
    const long i = ((long)blockIdx.x * 256 + threadIdx.x) * 4;
    float4 a = *(const float4*)&P2[i];
    float4 b = *(const float4*)&P2[3145728 + i];
    float4 c = *(const float4*)&AttnA[i];
    float4 d = *(const float4*)&Out[i];
    float4 o;
    o.x = a.x + b.x + c.x + d.x; o.y = a.y + b.y + c.y + d.y;
    o.z = a.z + b.z + c.z + d.z; o.w = a.w + b.w + c.w + d.w;
    *(float4*)&Out[i] = o;
}

// ---------------------------------------------------------------------------
// kernel_launch — algebraically fused attention:
//   Mt_h = Wk_h.Wq_h^T, Ut_h = Wo_h.Wv_h^T  (one merged 864-block launch)
//   per pair: {XM_h = x.Mt^T, Yt_h = (x.Ut^T)^T} ; Sc = XM.x^T (compact) ;
//   softmax ; AttnH[h] += P.Y (64-row blocks, non-atomic, h=1 in d_out)
// GEMM launches XCD-swizzled (T1). Workspace max offset 91,226,112 B.
// ---------------------------------------------------------------------------
extern "C" void kernel_launch(void* const* d_in, const int* in_sizes, int n_in,
                              void* d_out, int out_size, void* d_ws, size_t ws_size,
                              hipStream_t stream)
{
    // identify inputs by element count (x=3145728, ff=2359296, weights rest)
    int ix = -1, iw[4], nw = 0, iff[2], nf = 0;
    for (int i = 0; i < 7; ++i) {
        long sz = in_sizes[i];
        if (sz == 3145728L) ix = i;
        else if (sz == 2359296L) { if (nf < 2) iff[nf++] = i; }
        else { if (nw < 4) iw[nw++] = i; }
    }
    if (ix < 0 || nw != 4 || nf != 2) {
        ix = 0; iw[0] = 1; iw[1] = 2; iw[2] = 3; iw[3] = 4; iff[0] = 5; iff[1] = 6;
    }
    const float* x; const float *Wq, *Wk, *Wv, *Wo, *F1, *F2;
    x  = (const float*)d_in[ix];
    F1 = (const float*)d_in[iff[0]];
    F2 = (const float*)d_in[iff[1]];
    if (ix == 0) {           // dict order
        Wq = (const float*)d_in[iw[0]]; Wk = (const float*)d_in[iw[1]];
        Wv = (const float*)d_in[iw[2]]; Wo = (const float*)d_in[iw[3]];
    } else {                 // alphabetical
        Wk = (const float*)d_in[iw[0]]; Wo = (const float*)d_in[iw[1]];
        Wq = (const float*)d_in[iw[2]]; Wv = (const float*)d_in[iw[3]];
    }

    char* p = (char*)d_ws;
    // --- loop-phase layout ---
    ushort* Xb    = (ushort*)(p + 0);           // [4096,768] bf16      6,291,456
    ushort* Mt    = (ushort*)(p + 6291456);     // [12][768,768] bf16  14,155,776
    ushort* Ut    = (ushort*)(p + 20447232);    // [12][768,768] bf16  14,155,776
    float*  AttnA = (float*) (p + 34603008);    // [2][2048,768] fp32  12,582,912
    ushort* XMp   = (ushort*)(p + 47185920);    // [2][4096,768] bf16  12,582,912
    ushort* Yt    = (ushort*)(p + 59768832);    // [2][2][768,2048]    12,582,912
    ushort* Scp   = (ushort*)(p + 72351744);    // [2][2][136] tiles   17,825,792
    float*  AttnB = (float*)d_out;              // h=1 accumulator (12,582,912)
    // --- weight-fold transients (before loop; overlap AttnA/XMp/Yt/Scp) ---
    ushort* Wqb   = (ushort*)(p + 34603008);    // 14,155,776
    ushort* Wkb   = (ushort*)(p + 48758784);    // 14,155,776
    ushort* Wvb   = (ushort*)(p + 62914560);    // 14,155,776
    ushort* Wob   = (ushort*)(p + 77070336);    // 14,155,776 (ends 91,226,112)
    // --- FFN-phase layout (loop transients dead; AttnA preserved) ---
    ushort* H1    = (ushort*)(p + 0);           // [4096,3072] bf16    25,165,824
    ushort* F1b   = (ushort*)(p + 47185920);    // [3072,768] bf16      4,718,592
    ushort* F2b   = (ushort*)(p + 51904512);    // [768,3072] bf16      4,718,592
    ushort* Ln    = (ushort*)(p + 56623104);    // [4096,768] bf16      6,291,456
    float*  P2    = (float*) (p + 62914560);    // [2][4096,768] fp32  25,165,824

    dim3 blk(256);

    convert_kernel<<<dim3(1024), blk, 0, stream>>>(x,  Xb,  3145728L);
    convert_kernel<<<dim3(1024), blk, 0, stream>>>(Wq, Wqb, 7077888L);
    convert_kernel<<<dim3(1024), blk, 0, stream>>>(Wk, Wkb, 7077888L);
    convert_kernel<<<dim3(1024), blk, 0, stream>>>(Wv, Wvb, 7077888L);
    convert_kernel<<<dim3(1024), blk, 0, stream>>>(Wo, Wob, 7077888L);

    fold_kernel<<<dim3(6, 6, 24), blk, 0, stream>>>(Wqb, Wkb, Wvb, Wob, Mt, Ut);

    // weight buffers dead from here; AttnA region reusable
    hipMemsetAsync(AttnA, 0, 12582912, stream);
    hipMemsetAsync(AttnB, 0, 12582912, stream);

    for (int pr = 0; pr < 6; ++pr) {
        xmy_kernel<<<dim3(6, 32, 4), blk, 0, stream>>>(
            Xb, Mt + (size_t)pr * 1179648, Ut + (size_t)pr * 1179648,
            XMp, Yt);
        scores_c_kernel<<<dim3(136, 2, 2), blk, 0, stream>>>(XMp, Xb, Scp);
        softmax_c_kernel<<<dim3(8192), blk, 0, stream>>>(Scp);
        py_kernel<<<dim3(6, 32, 4), blk, 0, stream>>>(Scp, Yt, AttnA, AttnB);
    }

    convert_kernel<<<dim3(1024), blk, 0, stream>>>(F1, F1b, 2359296L);
    convert_kernel<<<dim3(1024), blk, 0, stream>>>(F2, F2b, 2359296L);
    ln_kernel<<<dim3(4096), blk, 0, stream>>>(AttnA, AttnB, Ln);
    ffn1_kernel<<<dim3(24, 32), blk, 0, stream>>>(Ln, F1b, H1);
    ffn2p_kernel<<<dim3(6, 32, 2), blk, 0, stream>>>(H1, F2b, P2);
    ffn2r_kernel<<<dim3(3072), blk, 0, stream>>>(P2, AttnA, (float*)d_out);
}

// Round 10
// 885.277 us; speedup vs baseline: 1.1445x; 1.0683x over previous
//
#include <hip/hip_runtime.h>
#include <math.h>

// B=2, S=2048, H=12, E(head width)=768=D, FF=3072
#define S_   2048
#define D_   768
#define HD_  9216
#define FF_  3072

typedef float  f32x4  __attribute__((ext_vector_type(4)));
typedef __bf16 bf16x8 __attribute__((ext_vector_type(8)));

__device__ __forceinline__ ushort f2bf(float v) {
    return __builtin_bit_cast(ushort, (__bf16)v);   // RNE fp32->bf16
}

// async global->LDS, 16B per lane; LDS dest = wave-uniform base + lane*16
__device__ __forceinline__ void load_lds16(const ushort* g, ushort* l) {
    __builtin_amdgcn_global_load_lds(
        (const __attribute__((address_space(1))) void*)g,
        (__attribute__((address_space(3))) void*)l, 16, 0, 0);
}

// ---------------------------------------------------------------------------
// Bijective XCD swizzle (T1): requires total grid % 8 == 0. Blocks with
// linear%8==c (which HW round-robins onto XCD c) get a CONTIGUOUS virtual
// range -> panel reuse becomes XCD-L2-local. Pure relabeling (bitwise-same).
// ---------------------------------------------------------------------------
__device__ __forceinline__ void xcd_swz(int& bx, int& by, int& bz) {
    const int gx = gridDim.x, gy = gridDim.y;
    const int nwg = gx * gy * (int)gridDim.z;
    int lin = bx + gx * (by + gy * bz);
    lin = (lin & 7) * (nwg >> 3) + (lin >> 3);
    bx = lin % gx;
    by = (lin / gx) % gy;
    bz = lin / (gx * gy);
}

// ---------------------------------------------------------------------------
// 128x128 bf16 MFMA core. BK=32, LDS 32 KiB, depth-1 prefetch 2-phase
// (R4-proven schedule). Conflict-free XOR swizzle (R6-proven, BANK_CONFLICT=0):
// 16B chunk c of row r stored at LDS chunk c^((r>>1)&3) via source-permuted
// global address (LDS dest linear); same XOR on the ds_read side.
// acc += A[M,K]*Bt[N,K]^T, fp32 acc.
// ---------------------------------------------------------------------------
__device__ __forceinline__ void gemm128(
    const ushort* __restrict__ A, int lda,
    const ushort* __restrict__ Bt, int ldb,
    int m0, int n0, int kmax, f32x4 acc[4][4])
{
    __shared__ __align__(16) ushort As[2][128 * 32];
    __shared__ __align__(16) ushort Bs[2][128 * 32];
    const int tid  = threadIdx.x;
    const int lane = tid & 63, wave = tid >> 6;
    const int l16  = lane & 15, quad = lane >> 4;
    const int wr = wave >> 1, wc = wave & 1;
    const int srow = lane >> 2;                                  // 0..15
    const int scol = ((lane & 3) ^ ((srow >> 1) & 3)) << 3;      // swizzled src

    const ushort* Ab = A + (size_t)m0 * lda;
    const ushort* Bb = Bt + (size_t)n0 * ldb;

    auto stage = [&](int k0, int buf) {
#pragma unroll
        for (int c = 0; c < 2; ++c) {
            const int rb = c * 64 + wave * 16;                   // uniform base
            load_lds16(Ab + (size_t)(rb + srow) * lda + k0 + scol,
                       &As[buf][rb * 32]);
            load_lds16(Bb + (size_t)(rb + srow) * ldb + k0 + scol,
                       &Bs[buf][rb * 32]);
        }
    };

    stage(0, 0);
    __syncthreads();                       // buf0 ready
    const int csw = (quad ^ ((l16 >> 1) & 3)) << 3;
    int cur = 0;
    for (int k0 = 0; k0 < kmax; k0 += 32) {
        if (k0 + 32 < kmax) stage(k0 + 32, cur ^ 1);   // prefetch next tile
        bf16x8 a[4], b[4];
#pragma unroll
        for (int i = 0; i < 4; ++i)
            a[i] = *(const bf16x8*)&As[cur][(wr * 64 + i * 16 + l16) * 32 + csw];
#pragma unroll
        for (int j = 0; j < 4; ++j)
            b[j] = *(const bf16x8*)&Bs[cur][(wc * 64 + j * 16 + l16) * 32 + csw];
#pragma unroll
        for (int i = 0; i < 4; ++i)
#pragma unroll
            for (int j = 0; j < 4; ++j)
                acc[i][j] = __builtin_amdgcn_mfma_f32_16x16x32_bf16(
                    a[i], b[j], acc[i][j], 0, 0, 0);
        __syncthreads();                   // drains prefetch vmcnt; syncs reuse
        cur ^= 1;
    }
}

// ---------------------------------------------------------------------------
// 64x128 core, A in causally-compacted tile layout: element (r, k) lives at
// Ab[(k>>7)*16384 + r*128 + (k&127)], Ab points at the first row used.
// kmax multiple of 128. 2x2 waves, each 32x64; acc[2][4]. LDS 24 KiB.
// ---------------------------------------------------------------------------
__device__ __forceinline__ void gemm64_bA(
    const ushort* __restrict__ Ab,
    const ushort* __restrict__ Bt, int ldb,
    int n0, int kmax, f32x4 acc[2][4])
{
    __shared__ __align__(16) ushort As[2][64 * 32];
    __shared__ __align__(16) ushort Bs[2][128 * 32];
    const int tid  = threadIdx.x;
    const int lane = tid & 63, wave = tid >> 6;
    const int l16  = lane & 15, quad = lane >> 4;
    const int wr = wave >> 1, wc = wave & 1;
    const int srow = lane >> 2;
    const int scol = ((lane & 3) ^ ((srow >> 1) & 3)) << 3;

    const ushort* Bb = Bt + (size_t)n0 * ldb;

    auto stage = [&](int k0, int buf) {
        const ushort* At = Ab + (size_t)(k0 >> 7) * 16384 + (k0 & 127);
        {
            const int rb = wave * 16;
            load_lds16(At + (size_t)(rb + srow) * 128 + scol, &As[buf][rb * 32]);
        }
#pragma unroll
        for (int c = 0; c < 2; ++c) {
            const int rb = c * 64 + wave * 16;
            load_lds16(Bb + (size_t)(rb + srow) * ldb + k0 + scol,
                       &Bs[buf][rb * 32]);
        }
    };

    stage(0, 0);
    __syncthreads();
    const int csw = (quad ^ ((l16 >> 1) & 3)) << 3;
    int cur = 0;
    for (int k0 = 0; k0 < kmax; k0 += 32) {
        if (k0 + 32 < kmax) stage(k0 + 32, cur ^ 1);
        bf16x8 a[2], b[4];
#pragma unroll
        for (int i = 0; i < 2; ++i)
            a[i] = *(const bf16x8*)&As[cur][(wr * 32 + i * 16 + l16) * 32 + csw];
#pragma unroll
        for (int j = 0; j < 4; ++j)
            b[j] = *(const bf16x8*)&Bs[cur][(wc * 64 + j * 16 + l16) * 32 + csw];
#pragma unroll
        for (int i = 0; i < 2; ++i)
#pragma unroll
            for (int j = 0; j < 4; ++j)
                acc[i][j] = __builtin_amdgcn_mfma_f32_16x16x32_bf16(
                    a[i], b[j], acc[i][j], 0, 0, 0);
        __syncthreads();
        cur ^= 1;
    }
}

// epilogue index helpers (verified C/D layout: col=lane&15, row=quad*4+reg)
#define EPI_DECL \
    const int lane_ = threadIdx.x & 63, wave_ = threadIdx.x >> 6;   \
    const int l16_ = lane_ & 15, quad_ = lane_ >> 4;                \
    const int wr_ = wave_ >> 1, wc_ = wave_ & 1;
#define RR_ (wr_ * 64 + i * 16 + quad_ * 4 + r)
#define NC_ (wc_ * 64 + j * 16 + l16_)
#define RR64_ (wr_ * 32 + i * 16 + quad_ * 4 + r)

// ---------------------------------------------------------------------------
// Batched fp32 -> bf16 convert: up to 5 tensors in one launch (z selects).
// Each n must be a multiple of 1024 (or 0 to skip the slot).
// ---------------------------------------------------------------------------
__global__ __launch_bounds__(256) void convert5_kernel(
    const float* __restrict__ p0, ushort* __restrict__ q0, long n0,
    const float* __restrict__ p1, ushort* __restrict__ q1, long n1,
    const float* __restrict__ p2, ushort* __restrict__ q2, long n2,
    const float* __restrict__ p3, ushort* __restrict__ q3, long n3,
    const float* __restrict__ p4, ushort* __restrict__ q4, long n4)
{
    const int z = blockIdx.y;
    const float* in = (z == 0) ? p0 : (z == 1) ? p1 : (z == 2) ? p2
                     : (z == 3) ? p3 : p4;
    ushort* out = (z == 0) ? q0 : (z == 1) ? q1 : (z == 2) ? q2
                 : (z == 3) ? q3 : q4;
    const long n = (z == 0) ? n0 : (z == 1) ? n1 : (z == 2) ? n2
                  : (z == 3) ? n3 : n4;
    long i = ((long)blockIdx.x * 256 + threadIdx.x) * 4;
    const long stride = (long)gridDim.x * 1024;
    for (; i < n; i += stride) {
        float4 v = *(const float4*)&in[i];
        out[i + 0] = f2bf(v.x); out[i + 1] = f2bf(v.y);
        out[i + 2] = f2bf(v.z); out[i + 3] = f2bf(v.w);
    }
}

// ---------------------------------------------------------------------------
// Weight folds, both in ONE launch. z<12: Mt_h = Wkb_h . Wqb_h^T.
// z>=12: Ut_h = Wob[:, h*768:+768] . Wvb_h^T. grid (6, 6, 24) = 864 blocks.
// XCD-swizzled: each XCD works 3 contiguous z-slices (panels ~2.4MB -> L2).
// ---------------------------------------------------------------------------
__global__ __launch_bounds__(256, 2) void fold_kernel(
    const ushort* __restrict__ Wqb, const ushort* __restrict__ Wkb,
    const ushort* __restrict__ Wvb, const ushort* __restrict__ Wob,
    ushort* __restrict__ Mt, ushort* __restrict__ Ut)
{
    int bx = blockIdx.x, by = blockIdx.y, bz = blockIdx.z;
    xcd_swz(bx, by, bz);
    const int z = bz;
    const int m0 = by * 128, n0 = bx * 128;
    f32x4 acc[4][4];
#pragma unroll
    for (int i = 0; i < 4; ++i)
#pragma unroll
        for (int j = 0; j < 4; ++j) acc[i][j] = (f32x4){0.f, 0.f, 0.f, 0.f};
    ushort* out;
    if (z < 12) {
        gemm128(Wkb + (size_t)z * 589824, 768, Wqb + (size_t)z * 589824, 768,
                m0, n0, 768, acc);
        out = Mt + (size_t)z * 589824;
    } else {
        const int h = z - 12;
        gemm128(Wob + (size_t)h * 768, HD_, Wvb + (size_t)h * 589824, 768,
                m0, n0, 768, acc);
        out = Ut + (size_t)h * 589824;
    }
    EPI_DECL
#pragma unroll
    for (int i = 0; i < 4; ++i)
#pragma unroll
        for (int j = 0; j < 4; ++j)
#pragma unroll
            for (int r = 0; r < 4; ++r)
                out[(size_t)(m0 + RR_) * D_ + n0 + NC_] = f2bf(acc[i][j][r]);
}

// ---------------------------------------------------------------------------
// XM + Y for one head pair. z=0,1: XM_h = x.Mt_h^T (normal write).
// z=2,3: Y_h = x.Ut_h^T, written TRANSPOSED: Yt[h][slab][768][2048].
// grid (6, 32, 4) = 768 blocks, XCD-swizzled.
// ---------------------------------------------------------------------------
__global__ __launch_bounds__(256, 2) void xmy_kernel(
    const ushort* __restrict__ Xb, const ushort* __restrict__ MtP,
    const ushort* __restrict__ UtP, ushort* __restrict__ XMp,
    ushort* __restrict__ Yt)
{
    int bx = blockIdx.x, by = blockIdx.y, bz = blockIdx.z;
    xcd_swz(bx, by, bz);
    const int z = bz;
    const int h = z & 1;
    const bool ymode = z >= 2;
    const int m0 = by * 128, n0 = bx * 128;
    const ushort* Bt = (ymode ? UtP : MtP) + (size_t)h * 589824;
    f32x4 acc[4][4];
#pragma unroll
    for (int i = 0; i < 4; ++i)
#pragma unroll
        for (int j = 0; j < 4; ++j) acc[i][j] = (f32x4){0.f, 0.f, 0.f, 0.f};
    gemm128(Xb, D_, Bt, D_, m0, n0, D_, acc);
    EPI_DECL
    if (!ymode) {
        ushort* out = XMp + (size_t)h * 3145728;
#pragma unroll
        for (int i = 0; i < 4; ++i)
#pragma unroll
            for (int j = 0; j < 4; ++j)
#pragma unroll
                for (int r = 0; r < 4; ++r)
                    out[(size_t)(m0 + RR_) * D_ + n0 + NC_] = f2bf(acc[i][j][r]);
    } else {
        const int b = m0 >> 11;
        ushort* out = Yt + (size_t)h * 3145728 + (size_t)b * 1572864;
#pragma unroll
        for (int i = 0; i < 4; ++i)
#pragma unroll
            for (int j = 0; j < 4; ++j) {
                ushort4 o4;
                o4.x = f2bf(acc[i][j][0]); o4.y = f2bf(acc[i][j][1]);
                o4.z = f2bf(acc[i][j][2]); o4.w = f2bf(acc[i][j][3]);
                const int nc = n0 + wc_ * 64 + j * 16 + l16_;
                const int s  = (m0 & 2047) + wr_ * 64 + i * 16 + quad_ * 4;
                *(ushort4*)&out[(size_t)nc * 2048 + s] = o4;
            }
    }
}

// ---------------------------------------------------------------------------
// scores (compact, 128^2 tiles): tile t=(mi,ni), ni<=mi;
// Sc tile = XM.x^T (unscaled). grid (136, 2, 2) = 544 blocks, XCD-swizzled.
// ---------------------------------------------------------------------------
__global__ __launch_bounds__(256, 2) void scores_c_kernel(
    const ushort* __restrict__ XM, const ushort* __restrict__ Xb,
    ushort* __restrict__ Sc)
{
    int bx = blockIdx.x, by = blockIdx.y, bz = blockIdx.z;
    xcd_swz(bx, by, bz);
    const int t = bx, b = by, hp = bz;
    int mi = (int)((sqrtf(8.f * t + 1.f) - 1.f) * 0.5f);
    while ((mi + 1) * (mi + 2) / 2 <= t) ++mi;
    while (mi * (mi + 1) / 2 > t) --mi;
    const int ni = t - mi * (mi + 1) / 2;
    f32x4 acc[4][4];
#pragma unroll
    for (int i = 0; i < 4; ++i)
#pragma unroll
        for (int j = 0; j < 4; ++j) acc[i][j] = (f32x4){0.f, 0.f, 0.f, 0.f};
    gemm128(XM + (size_t)hp * 3145728 + (size_t)b * 1572864, D_,
            Xb + (size_t)b * 1572864, D_, mi * 128, ni * 128, D_, acc);
    ushort* out = Sc + ((size_t)(hp * 2 + b) * 136 + t) * 16384;
    EPI_DECL
#pragma unroll
    for (int i = 0; i < 4; ++i)
#pragma unroll
        for (int j = 0; j < 4; ++j)
#pragma unroll
            for (int r = 0; r < 4; ++r)
                out[(size_t)RR_ * 128 + NC_] = f2bf(acc[i][j][r]);
}

// ---------------------------------------------------------------------------
// Causal softmax in place on compact tiles (scale 1/sqrt(768)); zeros k>q.
// Writes the FULL (mi+1)*128-wide row (zeros beyond q) -- py relies on this.
// Vectorized ushort4 access. grid (2 hp * 2 slab * 2048 rows) = 8192.
// ---------------------------------------------------------------------------
__global__ __launch_bounds__(256) void softmax_c_kernel(ushort* __restrict__ Sc)
{
    const int bx = blockIdx.x;
    const int hp = bx >> 12, b = (bx >> 11) & 1, q = bx & 2047;
    ushort* base = Sc + (size_t)((hp * 2 + b) * 136) * 16384;
    const int mi = q >> 7, tri = mi * (mi + 1) / 2;
    const int L  = (mi + 1) << 7;                   // row length
    const int ro = (q & 127) << 7;
    const float scale = 0.03608439182435161f;       // 1/sqrt(768)
    const int tid = threadIdx.x;
    const int wave = tid >> 6, lane = tid & 63;

    // element k lives at base[(tri + (k>>7))*16384 + ro + (k&127)]
    float xv[8];
    float m = -1e30f;
#pragma unroll
    for (int i = 0; i < 2; ++i) {
        const int k = tid * 4 + i * 1024;
        ushort4 v = {0, 0, 0, 0};
        if (k <= q)
            v = *(const ushort4*)&base[(size_t)(tri + (k >> 7)) * 16384
                                       + ro + (k & 127)];
        xv[i * 4 + 0] = (k + 0 <= q) ? (float)*(__bf16*)&v.x * scale : -1e30f;
        xv[i * 4 + 1] = (k + 1 <= q) ? (float)*(__bf16*)&v.y * scale : -1e30f;
        xv[i * 4 + 2] = (k + 2 <= q) ? (float)*(__bf16*)&v.z * scale : -1e30f;
        xv[i * 4 + 3] = (k + 3 <= q) ? (float)*(__bf16*)&v.w * scale : -1e30f;
#pragma unroll
        for (int j = 0; j < 4; ++j) m = fmaxf(m, xv[i * 4 + j]);
    }
    for (int o = 32; o > 0; o >>= 1) m = fmaxf(m, __shfl_xor(m, o));
    __shared__ float redm[4];
    if (lane == 0) redm[wave] = m;
    __syncthreads();
    m = fmaxf(fmaxf(redm[0], redm[1]), fmaxf(redm[2], redm[3]));

    float e[8];
    float s = 0.f;
#pragma unroll
    for (int i = 0; i < 2; ++i) {
        const int k = tid * 4 + i * 1024;
#pragma unroll
        for (int j = 0; j < 4; ++j) {
            e[i * 4 + j] = (k + j <= q) ? __expf(xv[i * 4 + j] - m) : 0.f;
            s += e[i * 4 + j];
        }
    }
    for (int o = 32; o > 0; o >>= 1) s += __shfl_xor(s, o);
    __shared__ float reds[4];
    if (lane == 0) reds[wave] = s;
    __syncthreads();
    s = reds[0] + reds[1] + reds[2] + reds[3];
    const float inv = 1.f / s;
#pragma unroll
    for (int i = 0; i < 2; ++i) {
        const int k = tid * 4 + i * 1024;
        if (k < L) {
            ushort4 o4;
            o4.x = f2bf(e[i * 4 + 0] * inv);
            o4.y = f2bf(e[i * 4 + 1] * inv);
            o4.z = f2bf(e[i * 4 + 2] * inv);
            o4.w = f2bf(e[i * 4 + 3] * inv);
            *(ushort4*)&base[(size_t)(tri + (k >> 7)) * 16384
                             + ro + (k & 127)] = o4;
        }
    }
}

// ---------------------------------------------------------------------------
// AttnH[h] ?= P_h . Y_h  (compact A, 64-row q-sub-tiles). grid (6, 32, 4).
// Locality+balance remap: XCD c (lin%8) gets contiguous 96-virt chunk = half
// of one z=(h,b) -> that z's Yt panel (3.1MB) stays L2-resident. Within a
// chunk n0 runs fastest (A-tile reuse) and mi64 uses the balanced interleave
// (g even -> 31-g/2 heavy, g odd -> g/2 light; each 16-group chunk sums to
// 136 work units). first=1: store (replaces memset); else accumulate.
// Heads write disjoint accumulators (AttnA ws, AttnB d_out) -> no atomics.
// ---------------------------------------------------------------------------
__global__ __launch_bounds__(256, 2) void py_kernel(
    const ushort* __restrict__ Sc, const ushort* __restrict__ Yt,
    float* __restrict__ AttnA, float* __restrict__ AttnB, int first)
{
    const int lin  = blockIdx.x + 6 * (blockIdx.y + 32 * blockIdx.z);
    const int virt = (lin & 7) * 96 + (lin >> 3);
    const int z  = virt / 192;                 // (h,b)
    const int v  = virt % 192;
    const int g  = v / 6;                      // 0..31
    const int n0 = (v % 6) * 128;
    const int mi64 = (g & 1) ? (g >> 1) : (31 - (g >> 1));   // balanced
    const int h = z >> 1, b = z & 1;
    const int mi = mi64 >> 1;                  // 128-row tile index
    const ushort* Ab =
        Sc + ((size_t)(h * 2 + b) * 136 + mi * (mi + 1) / 2) * 16384
           + (size_t)(mi64 & 1) * 8192;        // 64-row offset inside tile
    const ushort* Bt = Yt + (size_t)h * 3145728 + (size_t)b * 1572864;
    f32x4 acc[2][4];
#pragma unroll
    for (int i = 0; i < 2; ++i)
#pragma unroll
        for (int j = 0; j < 4; ++j) acc[i][j] = (f32x4){0.f, 0.f, 0.f, 0.f};
    gemm64_bA(Ab, Bt, S_, n0, (mi + 1) << 7, acc);
    float* out = (h ? AttnB : AttnA) + (size_t)b * 1572864
               + (size_t)mi64 * 64 * D_;
    EPI_DECL
    if (first) {
#pragma unroll
        for (int i = 0; i < 2; ++i)
#pragma unroll
            for (int j = 0; j < 4; ++j)
#pragma unroll
                for (int r = 0; r < 4; ++r)
                    out[(size_t)RR64_ * D_ + n0 + NC_] = acc[i][j][r];
    } else {
#pragma unroll
        for (int i = 0; i < 2; ++i)
#pragma unroll
            for (int j = 0; j < 4; ++j)
#pragma unroll
                for (int r = 0; r < 4; ++r)
                    out[(size_t)RR64_ * D_ + n0 + NC_] += acc[i][j][r];
    }
}

// ---------------------------------------------------------------------------
// LayerNorm (no affine, eps=1e-5) of (AttnA+AttnB): fp32 in -> bf16 out.
// grid (4096).
// ---------------------------------------------------------------------------
__global__ __launch_bounds__(256) void ln_kernel(
    const float* __restrict__ AttnA, const float* __restrict__ AttnB,
    ushort* __restrict__ Ln)
{
    const int row = blockIdx.x;
    const float* a = AttnA + (size_t)row * D_;
    const float* b = AttnB + (size_t)row * D_;
    const int tid = threadIdx.x;
    const int wave = tid >> 6, lane = tid & 63;
    float v0 = a[tid]       + b[tid];
    float v1 = a[tid + 256] + b[tid + 256];
    float v2 = a[tid + 512] + b[tid + 512];
    float s  = v0 + v1 + v2;
    float sq = v0 * v0 + v1 * v1 + v2 * v2;
    for (int o = 32; o > 0; o >>= 1) { s += __shfl_xor(s, o); sq += __shfl_xor(sq, o); }
    __shared__ float rs[4], rq[4];
    if (lane == 0) { rs[wave] = s; rq[wave] = sq; }
    __syncthreads();
    s  = rs[0] + rs[1] + rs[2] + rs[3];
    sq = rq[0] + rq[1] + rq[2] + rq[3];
    const float mean = s * (1.f / 768.f);
    float var = sq * (1.f / 768.f) - mean * mean;
    var = fmaxf(var, 0.f);
    const float rstd = rsqrtf(var + 1e-5f);
    ushort* o = Ln + (size_t)row * D_;
    o[tid]       = f2bf((v0 - mean) * rstd);
    o[tid + 256] = f2bf((v1 - mean) * rstd);
    o[tid + 512] = f2bf((v2 - mean) * rstd);
}

// ---------------------------------------------------------------------------
// FFN1 + exact GELU: H1 = gelu(Ln . F1b^T), [4096,3072]. grid (24, 32),
// XCD-swizzled.
// ---------------------------------------------------------------------------
__global__ __launch_bounds__(256, 2) void ffn1_kernel(
    const ushort* __restrict__ Ln, const ushort* __restrict__ F1b,
    ushort* __restrict__ H1)
{
    int bx = blockIdx.x, by = blockIdx.y, bz = blockIdx.z;
    xcd_swz(bx, by, bz);
    const int m0 = by * 128, n0 = bx * 128;
    f32x4 acc[4][4];
#pragma unroll
    for (int i = 0; i < 4; ++i)
#pragma unroll
        for (int j = 0; j < 4; ++j) acc[i][j] = (f32x4){0.f, 0.f, 0.f, 0.f};
    gemm128(Ln, D_, F1b, D_, m0, n0, D_, acc);
    EPI_DECL
#pragma unroll
    for (int i = 0; i < 4; ++i)
#pragma unroll
        for (int j = 0; j < 4; ++j)
#pragma unroll
            for (int r = 0; r < 4; ++r) {
                float v = acc[i][j][r];
                float gl = 0.5f * v * (1.f + erff(v * 0.70710678118654752f));
                H1[(size_t)(m0 + RR_) * FF_ + n0 + NC_] = f2bf(gl);
            }
}

// ---------------------------------------------------------------------------
// FFN2 split-K=2 (128-row): P2[z] = H1[:,z*1536:+1536].F2b^T slice.
// grid (6, 32, 2) = 384 blocks, XCD-swizzled. No atomics.
// ---------------------------------------------------------------------------
__global__ __launch_bounds__(256, 2) void ffn2p_kernel(
    const ushort* __restrict__ H1, const ushort* __restrict__ F2b,
    float* __restrict__ P2)
{
    int bx = blockIdx.x, by = blockIdx.y, bz = blockIdx.z;
    xcd_swz(bx, by, bz);
    const int z = bz;
    const int m0 = by * 128, n0 = bx * 128;
    f32x4 acc[4][4];
#pragma unroll
    for (int i = 0; i < 4; ++i)
#pragma unroll
        for (int j = 0; j < 4; ++j) acc[i][j] = (f32x4){0.f, 0.f, 0.f, 0.f};
    gemm128(H1 + (size_t)z * 1536, FF_, F2b + (size_t)z * 1536, FF_,
            m0, n0, 1536, acc);
    float* out = P2 + (size_t)z * 3145728;
    EPI_DECL
#pragma unroll
    for (int i = 0; i < 4; ++i)
#pragma unroll
        for (int j = 0; j < 4; ++j)
#pragma unroll
            for (int r = 0; r < 4; ++r)
                out[(size_t)(m0 + RR_) * D_ + n0 + NC_] = acc[i][j][r];
}

// ---------------------------------------------------------------------------
// FFN2 reduce + residual: Out = P2[0] + P2[1] + AttnA + AttnB.
// Out aliases AttnB (d_out): elementwise read-then-write, safe. grid (3072).
// ---------------------------------------------------------------------------
__global__ __launch_bounds__(256) void ffn2r_kernel(
    const float* __restrict__ P2, const float* __restrict__ AttnA,
    float* __restrict__ Out)
{
    const long i = ((long)blockIdx.x * 256 + threadIdx.x) * 4;
    float4 a = *(const float4*)&P2[i];
    float4 b = *(const float4*)&P2[3145728 + i];
    float4 c = *(const float4*)&AttnA[i];
    float4 d = *(const float4*)&Out[i];
    float4 o;
    o.x = a.x + b.x + c.x + d.x; o.y = a.y + b.y + c.y + d.y;
    o.z = a.z + b.z + c.z + d.z; o.w = a.w + b.w + c.w + d.w;
    *(float4*)&Out[i] = o;
}

// ---------------------------------------------------------------------------
// kernel_launch — algebraically fused attention:
//   Mt_h = Wk_h.Wq_h^T, Ut_h = Wo_h.Wv_h^T  (one merged 864-block launch)
//   per pair: {XM_h = x.Mt^T, Yt_h = (x.Ut^T)^T} ; Sc = XM.x^T (compact) ;
//   softmax ; AttnH[h] ?= P.Y (64-row, L2-chunked remap, first-store)
// GEMM launches XCD-swizzled (T1). Workspace max offset 91,226,112 B.
// ---------------------------------------------------------------------------
extern "C" void kernel_launch(void* const* d_in, const int* in_sizes, int n_in,
                              void* d_out, int out_size, void* d_ws, size_t ws_size,
                              hipStream_t stream)
{
    // identify inputs by element count (x=3145728, ff=2359296, weights rest)
    int ix = -1, iw[4], nw = 0, iff[2], nf = 0;
    for (int i = 0; i < 7; ++i) {
        long sz = in_sizes[i];
        if (sz == 3145728L) ix = i;
        else if (sz == 2359296L) { if (nf < 2) iff[nf++] = i; }
        else { if (nw < 4) iw[nw++] = i; }
    }
    if (ix < 0 || nw != 4 || nf != 2) {
        ix = 0; iw[0] = 1; iw[1] = 2; iw[2] = 3; iw[3] = 4; iff[0] = 5; iff[1] = 6;
    }
    const float* x; const float *Wq, *Wk, *Wv, *Wo, *F1, *F2;
    x  = (const float*)d_in[ix];
    F1 = (const float*)d_in[iff[0]];
    F2 = (const float*)d_in[iff[1]];
    if (ix == 0) {           // dict order
        Wq = (const float*)d_in[iw[0]]; Wk = (const float*)d_in[iw[1]];
        Wv = (const float*)d_in[iw[2]]; Wo = (const float*)d_in[iw[3]];
    } else {                 // alphabetical
        Wk = (const float*)d_in[iw[0]]; Wo = (const float*)d_in[iw[1]];
        Wq = (const float*)d_in[iw[2]]; Wv = (const float*)d_in[iw[3]];
    }

    char* p = (char*)d_ws;
    // --- loop-phase layout ---
    ushort* Xb    = (ushort*)(p + 0);           // [4096,768] bf16      6,291,456
    ushort* Mt    = (ushort*)(p + 6291456);     // [12][768,768] bf16  14,155,776
    ushort* Ut    = (ushort*)(p + 20447232);    // [12][768,768] bf16  14,155,776
    float*  AttnA = (float*) (p + 34603008);    // [2][2048,768] fp32  12,582,912
    ushort* XMp   = (ushort*)(p + 47185920);    // [2][4096,768] bf16  12,582,912
    ushort* Yt    = (ushort*)(p + 59768832);    // [2][2][768,2048]    12,582,912
    ushort* Scp   = (ushort*)(p + 72351744);    // [2][2][136] tiles   17,825,792
    float*  AttnB = (float*)d_out;              // h=1 accumulator (12,582,912)
    // --- weight-fold transients (before loop; overlap AttnA/XMp/Yt/Scp) ---
    ushort* Wqb   = (ushort*)(p + 34603008);    // 14,155,776
    ushort* Wkb   = (ushort*)(p + 48758784);    // 14,155,776
    ushort* Wvb   = (ushort*)(p + 62914560);    // 14,155,776
    ushort* Wob   = (ushort*)(p + 77070336);    // 14,155,776 (ends 91,226,112)
    // --- FFN-phase layout (loop transients dead; AttnA preserved) ---
    ushort* H1    = (ushort*)(p + 0);           // [4096,3072] bf16    25,165,824
    ushort* F1b   = (ushort*)(p + 47185920);    // [3072,768] bf16      4,718,592
    ushort* F2b   = (ushort*)(p + 51904512);    // [768,3072] bf16      4,718,592
    ushort* Ln    = (ushort*)(p + 56623104);    // [4096,768] bf16      6,291,456
    float*  P2    = (float*) (p + 62914560);    // [2][4096,768] fp32  25,165,824

    dim3 blk(256);

    // all 5 input converts in one launch
    convert5_kernel<<<dim3(1024, 5), blk, 0, stream>>>(
        x,  Xb,  3145728L,
        Wq, Wqb, 7077888L,
        Wk, Wkb, 7077888L,
        Wv, Wvb, 7077888L,
        Wo, Wob, 7077888L);

    fold_kernel<<<dim3(6, 6, 24), blk, 0, stream>>>(Wqb, Wkb, Wvb, Wob, Mt, Ut);

    for (int pr = 0; pr < 6; ++pr) {
        xmy_kernel<<<dim3(6, 32, 4), blk, 0, stream>>>(
            Xb, Mt + (size_t)pr * 1179648, Ut + (size_t)pr * 1179648,
            XMp, Yt);
        scores_c_kernel<<<dim3(136, 2, 2), blk, 0, stream>>>(XMp, Xb, Scp);
        softmax_c_kernel<<<dim3(8192), blk, 0, stream>>>(Scp);
        py_kernel<<<dim3(6, 32, 4), blk, 0, stream>>>(
            Scp, Yt, AttnA, AttnB, pr == 0 ? 1 : 0);
    }

    convert5_kernel<<<dim3(1024, 2), blk, 0, stream>>>(
        F1, F1b, 2359296L,
        F2, F2b, 2359296L,
        (const float*)nullptr, (ushort*)nullptr, 0L,
        (const float*)nullptr, (ushort*)nullptr, 0L,
        (const float*)nullptr, (ushort*)nullptr, 0L);
    ln_kernel<<<dim3(4096), blk, 0, stream>>>(AttnA, AttnB, Ln);
    ffn1_kernel<<<dim3(24, 32), blk, 0, stream>>>(Ln, F1b, H1);
    ffn2p_kernel<<<dim3(6, 32, 2), blk, 0, stream>>>(H1, F2b, P2);
    ffn2r_kernel<<<dim3(3072), blk, 0, stream>>>(P2, AttnA, (float*)d_out);
}